// Round 6
// baseline (2570.788 us; speedup 1.0000x reference)
//
#include <hip/hip_runtime.h>
#include <hip/hip_bf16.h>
#include <cstdint>

#define T_DIM 4096
#define D_DIM 4096
#define I_DIM 12288
#define GRP   128

typedef __attribute__((ext_vector_type(8))) short bf16x8;   // MFMA A/B frag (8 bf16)
typedef __attribute__((ext_vector_type(4))) float f32x4;    // MFMA C/D frag
typedef __attribute__((ext_vector_type(4))) int   int32x4;

typedef __attribute__((address_space(3))) void lds_void;
typedef const __attribute__((address_space(1))) void gmem_void;

// f32 -> bf16 bits, round-to-nearest-even (finite inputs)
static __device__ __forceinline__ unsigned short f2bf(float f) {
    unsigned int u = __float_as_uint(f);
    u += 0x7FFFu + ((u >> 16) & 1u);
    return (unsigned short)(u >> 16);
}
static __device__ __forceinline__ float bf2f(unsigned short b) {
    return __uint_as_float(((unsigned int)b) << 16);
}

// ---------------- Hadamard (blockwise-128 FWHT), one wave per group, 2 elems/lane ----
__global__ void had_f32_to_bf16(const float* __restrict__ in, unsigned short* __restrict__ out,
                                int ngroups) {
    int gid = blockIdx.x * (blockDim.x >> 6) + (threadIdx.x >> 6);
    if (gid >= ngroups) return;
    int lane = threadIdx.x & 63;
    const float2 v2 = *reinterpret_cast<const float2*>(in + (size_t)gid * 128 + lane * 2);
    float v0 = v2.x, v1 = v2.y;
    { float t0 = v0 + v1, t1 = v0 - v1; v0 = t0; v1 = t1; }
#pragma unroll
    for (int m = 1; m <= 32; m <<= 1) {
        float b0 = __shfl_xor(v0, m);
        float b1 = __shfl_xor(v1, m);
        if (lane & m) { v0 = b0 - v0; v1 = b1 - v1; }
        else          { v0 = v0 + b0; v1 = v1 + b1; }
    }
    const float s = 0.08838834764831843f;  // 1/sqrt(128)
    unsigned int o = (unsigned int)f2bf(v0 * s) | ((unsigned int)f2bf(v1 * s) << 16);
    *reinterpret_cast<unsigned int*>(out + (size_t)gid * 128 + lane * 2) = o;
}

__global__ void had_bf16_inplace(unsigned short* __restrict__ buf, int ngroups) {
    int gid = blockIdx.x * (blockDim.x >> 6) + (threadIdx.x >> 6);
    if (gid >= ngroups) return;
    int lane = threadIdx.x & 63;
    unsigned int pv = *reinterpret_cast<const unsigned int*>(buf + (size_t)gid * 128 + lane * 2);
    float v0 = __uint_as_float((pv & 0xFFFFu) << 16);
    float v1 = __uint_as_float(pv & 0xFFFF0000u);
    { float t0 = v0 + v1, t1 = v0 - v1; v0 = t0; v1 = t1; }
#pragma unroll
    for (int m = 1; m <= 32; m <<= 1) {
        float b0 = __shfl_xor(v0, m);
        float b1 = __shfl_xor(v1, m);
        if (lane & m) { v0 = b0 - v0; v1 = b1 - v1; }
        else          { v0 = v0 + b0; v1 = v1 + b1; }
    }
    const float s = 0.08838834764831843f;
    unsigned int o = (unsigned int)f2bf(v0 * s) | ((unsigned int)f2bf(v1 * s) << 16);
    *reinterpret_cast<unsigned int*>(buf + (size_t)gid * 128 + lane * 2) = o;
}

// ---------------- weight dequant: int4-in-int32 [O,In] -> bf16 [O,In] ----------------
__global__ void dequant_w(const int* __restrict__ Wq, const float* __restrict__ S,
                          unsigned short* __restrict__ Wbf, int In, int total8) {
    int t = blockIdx.x * blockDim.x + threadIdx.x;
    if (t >= total8) return;
    size_t base = (size_t)t * 8;
    size_t row = base / (size_t)In;
    int col = (int)(base - row * (size_t)In);
    float sc = S[row * (size_t)(In >> 7) + (col >> 7)];
    const int32x4* p = reinterpret_cast<const int32x4*>(Wq + base);
    int32x4 a = p[0], b = p[1];
    float nsc = -8.0f * sc;
    unsigned int o0 = (unsigned int)f2bf((float)a.x * sc + nsc) |
                      ((unsigned int)f2bf((float)a.y * sc + nsc) << 16);
    unsigned int o1 = (unsigned int)f2bf((float)a.z * sc + nsc) |
                      ((unsigned int)f2bf((float)a.w * sc + nsc) << 16);
    unsigned int o2 = (unsigned int)f2bf((float)b.x * sc + nsc) |
                      ((unsigned int)f2bf((float)b.y * sc + nsc) << 16);
    unsigned int o3 = (unsigned int)f2bf((float)b.z * sc + nsc) |
                      ((unsigned int)f2bf((float)b.w * sc + nsc) << 16);
    *reinterpret_cast<uint4*>(Wbf + base) = make_uint4(o0, o1, o2, o3);
}

// =====================================================================================
// 256x256 GEMM, 2 K-tiles/iter, 8 phases, 5-region LDS ring (3xA + 2xB = 160 KB),
// FRAG-REGISTER PIPELINE: phase p issues ds_reads for phase p+1's MFMA; lgkmcnt(N)
// retires the previous phase's reads (DS completes in order). STGs issue AFTER the
// MFMA cluster. vmcnt(6) at ph3/ph7; every retirement is 4-7 phases after issue.
// C[M,N] = A[M,K] @ W[N,K]^T, bf16 in. MODE 0: bf16 out; 1: silu(C)*acc in place; 2: f32.
// 8 waves (2M x 4N); per-wave 128x64; per phase: one m-quadrant (2m x 4n frags) x K=64.
// A regions: tile t -> t mod 3 (bases 0,16384,32768). B: even tiles -> B0_, odd -> B1_.
// Chunk-XOR swizzle c ^= (row&7), applied source-side for linear global_load_lds dest.
// =====================================================================================

#define GBAR()   __builtin_amdgcn_s_barrier()
#define LGKM(n)  asm volatile("s_waitcnt lgkmcnt(" #n ")" ::: "memory")
#define VMW(n)   asm volatile("s_waitcnt vmcnt(" #n ")" ::: "memory")
#define SB0()    __builtin_amdgcn_sched_barrier(0)
#define P1()     __builtin_amdgcn_s_setprio(1)
#define P0()     __builtin_amdgcn_s_setprio(0)

// stage half-tile (2 x global_load_lds, 16B/lane): src matrix, row0, region base (shorts)
#define STG(src, row0, base, h, kb)                                                    \
  { _Pragma("unroll")                                                                  \
    for (int i_ = 0; i_ < 2; ++i_) {                                                   \
      const int rl_ = (h) * 128 + i_ * 64 + (tid >> 3);                                \
      const int gs_ = (tid & 7) ^ ((tid >> 3) & 7);                                    \
      const unsigned short* gp_ = (src) + (size_t)((row0) + rl_) * K + (kb) + gs_ * 8; \
      unsigned short* lp_ = lds + (base) + ((h) * 128 + i_ * 64 + wid * 8) * 64;       \
      __builtin_amdgcn_global_load_lds((gmem_void*)gp_, (lds_void*)lp_, 16, 0, 0);     \
    } }

// read A frags for m-quadrant q into dst[2][2]
#define LDA(dst, base, q)                                                              \
  _Pragma("unroll")                                                                    \
  for (int mi_ = 0; mi_ < 2; ++mi_)                                                    \
  _Pragma("unroll")                                                                    \
  for (int ks_ = 0; ks_ < 2; ++ks_) {                                                  \
    int r_ = wr * 128 + (q) * 32 + mi_ * 16 + (lane & 15);                             \
    int c_ = ks_ * 4 + kc;                                                             \
    dst[mi_][ks_] = *reinterpret_cast<const bf16x8*>(                                  \
        lds + (base) + r_ * 64 + ((c_ ^ (r_ & 7)) << 3));                              \
  }

// read B frags (full K-tile) into dst[4][2]
#define LDB(dst, base)                                                                 \
  _Pragma("unroll")                                                                    \
  for (int ni_ = 0; ni_ < 4; ++ni_)                                                    \
  _Pragma("unroll")                                                                    \
  for (int ks_ = 0; ks_ < 2; ++ks_) {                                                  \
    int r_ = wc * 64 + ni_ * 16 + (lane & 15);                                         \
    int c_ = ks_ * 4 + kc;                                                             \
    dst[ni_][ks_] = *reinterpret_cast<const bf16x8*>(                                  \
        lds + (base) + r_ * 64 + ((c_ ^ (r_ & 7)) << 3));                              \
  }

#define MF16(q, afb, bkb)                                                              \
  _Pragma("unroll")                                                                    \
  for (int ks_ = 0; ks_ < 2; ++ks_)                                                    \
  _Pragma("unroll")                                                                    \
  for (int mi_ = 0; mi_ < 2; ++mi_)                                                    \
  _Pragma("unroll")                                                                    \
  for (int ni_ = 0; ni_ < 4; ++ni_)                                                    \
    acc[(q) * 2 + mi_][ni_] = __builtin_amdgcn_mfma_f32_16x16x32_bf16(                 \
        afb[mi_][ks_], bkb[ni_][ks_], acc[(q) * 2 + mi_][ni_], 0, 0, 0);

#define B0_ 49152
#define B1_ 65536

template<int MODE>
__global__ __launch_bounds__(512, 2)
void gemm256(const unsigned short* __restrict__ A,      // [M,K] bf16
             const unsigned short* __restrict__ W,      // [N,K] bf16
             void* __restrict__ C, int M, int N, int K)
{
    __shared__ __align__(16) unsigned short lds[81920];  // 160 KB: A0|A1|A2|B0|B1

    const int MT = M >> 8;
    const int nwg = gridDim.x;
    const int bid = blockIdx.x;
    const int cpx = nwg >> 3;                     // nwg % 8 == 0 in all our launches
    const int wg  = (bid & 7) * cpx + (bid >> 3); // bijective XCD swizzle
    const int m0 = (wg % MT) << 8;
    const int n0 = (wg / MT) << 8;

    const int tid  = threadIdx.x;
    const int lane = tid & 63;
    const int wid  = tid >> 6;
    const int wr = wid >> 2;                      // 0..1 (M half)
    const int wc = wid & 3;                       // 0..3 (N quarter)
    const int kc = lane >> 4;                     // 16B k-chunk selector

    f32x4 acc[8][4];
#pragma unroll
    for (int i = 0; i < 8; ++i)
#pragma unroll
        for (int j = 0; j < 4; ++j) acc[i][j] = (f32x4)0.0f;

    const int NT = K >> 6;                        // K-tiles (64 or 192)
    const int J  = NT >> 1;                       // iterations (>= 2)

    bf16x8 afA[2][2], afB[2][2], bkA[4][2], bkB[4][2];

    // ---- prologue ----
    STG(A, m0, 0, 0, 0);     STG(A, m0, 0, 1, 0);       // A(0) -> R0
    STG(W, n0, B0_, 0, 0);   STG(W, n0, B0_, 1, 0);     // B(0) -> B0
    VMW(0);
    GBAR();
    LDB(bkA, B0_);                                       // B(0) frags
    LDA(afA, 0, 0);                                      // A(0) q0 frags
    STG(A, m0, 16384, 0, 64); STG(A, m0, 16384, 1, 64); // A(1) -> R1
    STG(W, n0, B1_, 0, 64);   STG(W, n0, B1_, 1, 64);   // B(1) -> B1
    STG(A, m0, 32768, 0, 128);                          // A(2)h0 -> R2
    GBAR();

    int ra = 0, rb = 1, rc = 2;                   // A regions of tiles a, a+1, a+2

    for (int j = 0; j < J - 1; ++j) {
        const int a   = j << 1;
        const int kT2 = (a + 2) << 6;
        const int kT3 = (a + 3) << 6;
        const int kT4 = (a + 4) << 6;
        const int baA = ra << 14, bbA = rb << 14, bcA = rc << 14;

        // ---- ph1: compute a-q0; read A(a)q1 ----
        LDA(afB, baA, 1);
        LGKM(4); SB0();
        P1(); MF16(0, afA, bkA); P0();
        STG(W, n0, B0_, 0, kT2);                  // B(a+2)h0
        GBAR();
        // ---- ph2: a-q1; read q2 ----
        LDA(afA, baA, 2);
        LGKM(4); SB0();
        P1(); MF16(1, afB, bkA); P0();
        STG(W, n0, B0_, 1, kT2);                  // B(a+2)h1
        GBAR();
        // ---- ph3: a-q2; read q3 ----
        LDA(afB, baA, 3);
        LGKM(4); SB0();
        P1(); MF16(2, afA, bkA); P0();
        STG(A, m0, bcA, 1, kT2);                  // A(a+2)h1
        VMW(6);
        GBAR();
        // ---- ph4: a-q3; read B(a+1) + A(a+1)q0 ----
        LDB(bkB, B1_);
        LDA(afA, bbA, 0);
        LGKM(12); SB0();
        P1(); MF16(3, afB, bkA); P0();
        STG(A, m0, baA, 0, kT3);                  // A(a+3)h0
        GBAR();
        // ---- ph5: (a+1)-q0; read q1 ----
        LDA(afB, bbA, 1);
        LGKM(4); SB0();
        P1(); MF16(0, afA, bkB); P0();
        STG(A, m0, baA, 1, kT3);                  // A(a+3)h1
        GBAR();
        // ---- ph6: (a+1)-q1; read q2 ----
        LDA(afA, bbA, 2);
        LGKM(4); SB0();
        P1(); MF16(1, afB, bkB); P0();
        STG(W, n0, B1_, 0, kT3);                  // B(a+3)h0
        GBAR();
        // ---- ph7: (a+1)-q2; read q3 ----
        LDA(afB, bbA, 3);
        LGKM(4); SB0();
        P1(); MF16(2, afA, bkB); P0();
        STG(W, n0, B1_, 1, kT3);                  // B(a+3)h1
        VMW(6);
        GBAR();
        // ---- ph8: (a+1)-q3; read B(a+2) + A(a+2)q0 ----
        LDB(bkA, B0_);
        LDA(afA, bcA, 0);
        LGKM(12); SB0();
        P1(); MF16(3, afB, bkB); P0();
        if (j < J - 2) { STG(A, m0, bbA, 0, kT4); }  // A(a+4)h0
        GBAR();
        // rotate A ring: (ra, rb, rc) <- (rc, ra, rb)
        int t_ = ra; ra = rc; rc = rb; rb = t_;
    }

    // ---- peeled final iteration (tiles NT-2, NT-1): no staging ----
    {
        const int baA = ra << 14, bbA = rb << 14;
        LDA(afB, baA, 1);
        LGKM(4); SB0();
        P1(); MF16(0, afA, bkA); P0(); GBAR();
        LDA(afA, baA, 2);
        LGKM(4); SB0();
        P1(); MF16(1, afB, bkA); P0(); GBAR();
        LDA(afB, baA, 3);
        LGKM(4); SB0();
        P1(); MF16(2, afA, bkA); P0();
        VMW(0);
        GBAR();
        LDB(bkB, B1_);
        LDA(afA, bbA, 0);
        LGKM(12); SB0();
        P1(); MF16(3, afB, bkA); P0(); GBAR();
        LDA(afB, bbA, 1);
        LGKM(4); SB0();
        P1(); MF16(0, afA, bkB); P0(); GBAR();
        LDA(afA, bbA, 2);
        LGKM(4); SB0();
        P1(); MF16(1, afB, bkB); P0(); GBAR();
        LDA(afB, bbA, 3);
        LGKM(4); SB0();
        P1(); MF16(2, afA, bkB); P0(); GBAR();
        LGKM(0); SB0();
        P1(); MF16(3, afB, bkB); P0();
    }

    // ---- epilogue ----
#pragma unroll
    for (int mi = 0; mi < 8; ++mi)
#pragma unroll
        for (int ni = 0; ni < 4; ++ni) {
            const int col = n0 + (wc << 6) + ni * 16 + (lane & 15);
#pragma unroll
            for (int r = 0; r < 4; ++r) {
                const int row = m0 + (wr << 7) + mi * 16 + ((lane >> 4) << 2) + r;
                const size_t idx = (size_t)row * N + col;
                if (MODE == 2) {
                    ((float*)C)[idx] = acc[mi][ni][r];
                } else if (MODE == 0) {
                    ((unsigned short*)C)[idx] = f2bf(acc[mi][ni][r]);
                } else {
                    float g = bf2f(((unsigned short*)C)[idx]);
                    float u = acc[mi][ni][r];
                    float h = (g / (1.0f + __expf(-g))) * u;
                    ((unsigned short*)C)[idx] = f2bf(h);
                }
            }
        }
}

// ================== FALLBACK (round-1 verified): in-loop dequant GEMMs ==============
__global__ __launch_bounds__(256, 2)
void gemm_gateup_fb(const unsigned short* __restrict__ Xr,
                    const int* __restrict__ Wg, const float* __restrict__ Sg,
                    const int* __restrict__ Wu, const float* __restrict__ Su,
                    unsigned short* __restrict__ H)
{
    __shared__ __align__(16) unsigned short lA [128 * 64];
    __shared__ __align__(16) unsigned short lBg[128 * 64];
    __shared__ __align__(16) unsigned short lBu[128 * 64];
    const int MT = T_DIM / 128;
    const int bid = blockIdx.x;
    const int m0 = (bid % MT) * 128;
    const int n0 = (bid / MT) * 128;
    const int tid  = threadIdx.x;
    const int lane = tid & 63;
    const int wid  = tid >> 6;
    const int wr = wid >> 1, wc = wid & 1;
    f32x4 accG[4][4], accU[4][4];
#pragma unroll
    for (int i = 0; i < 4; ++i)
#pragma unroll
        for (int j = 0; j < 4; ++j) { accG[i][j] = (f32x4)0.0f; accU[i][j] = (f32x4)0.0f; }
    const int arow = lane >> 3;
    const int acol = (lane & 7) * 8;
    const int SStride = D_DIM / GRP;
    for (int k0 = 0; k0 < D_DIM; k0 += 64) {
        __syncthreads();
#pragma unroll
        for (int it = 0; it < 4; ++it) {
            int chunk = wid * 4 + it;
            const unsigned short* gp = Xr + (size_t)(m0 + chunk * 8 + arow) * D_DIM + k0 + acol;
            __builtin_amdgcn_global_load_lds((gmem_void*)gp, (lds_void*)(lA + chunk * 512), 16, 0, 0);
        }
        const int g = k0 >> 7;
#pragma unroll
        for (int i = 0; i < 8; ++i) {
            int linear = i * 1024 + tid * 4;
            int r = linear >> 6;
            int c = linear & 63;
            const int32x4 wg = *reinterpret_cast<const int32x4*>(Wg + (size_t)(n0 + r) * D_DIM + k0 + c);
            const int32x4 wu = *reinterpret_cast<const int32x4*>(Wu + (size_t)(n0 + r) * D_DIM + k0 + c);
            float scg = Sg[(size_t)(n0 + r) * SStride + g];
            float scu = Su[(size_t)(n0 + r) * SStride + g];
            unsigned int g01 = (unsigned int)f2bf((float)(wg.x - 8) * scg) | ((unsigned int)f2bf((float)(wg.y - 8) * scg) << 16);
            unsigned int g23 = (unsigned int)f2bf((float)(wg.z - 8) * scg) | ((unsigned int)f2bf((float)(wg.w - 8) * scg) << 16);
            unsigned int u01 = (unsigned int)f2bf((float)(wu.x - 8) * scu) | ((unsigned int)f2bf((float)(wu.y - 8) * scu) << 16);
            unsigned int u23 = (unsigned int)f2bf((float)(wu.z - 8) * scu) | ((unsigned int)f2bf((float)(wu.w - 8) * scu) << 16);
            *reinterpret_cast<uint2*>(lBg + r * 64 + c) = make_uint2(g01, g23);
            *reinterpret_cast<uint2*>(lBu + r * 64 + c) = make_uint2(u01, u23);
        }
        __syncthreads();
#pragma unroll
        for (int ks = 0; ks < 2; ++ks) {
            const int koff = ks * 32 + (lane >> 4) * 8;
            bf16x8 af[4], bg[4], bu[4];
#pragma unroll
            for (int mi = 0; mi < 4; ++mi)
                af[mi] = *reinterpret_cast<const bf16x8*>(lA + (wr * 64 + mi * 16 + (lane & 15)) * 64 + koff);
#pragma unroll
            for (int ni = 0; ni < 4; ++ni) {
                bg[ni] = *reinterpret_cast<const bf16x8*>(lBg + (wc * 64 + ni * 16 + (lane & 15)) * 64 + koff);
                bu[ni] = *reinterpret_cast<const bf16x8*>(lBu + (wc * 64 + ni * 16 + (lane & 15)) * 64 + koff);
            }
#pragma unroll
            for (int mi = 0; mi < 4; ++mi)
#pragma unroll
                for (int ni = 0; ni < 4; ++ni) {
                    accG[mi][ni] = __builtin_amdgcn_mfma_f32_16x16x32_bf16(af[mi], bg[ni], accG[mi][ni], 0, 0, 0);
                    accU[mi][ni] = __builtin_amdgcn_mfma_f32_16x16x32_bf16(af[mi], bu[ni], accU[mi][ni], 0, 0, 0);
                }
        }
    }
#pragma unroll
    for (int mi = 0; mi < 4; ++mi)
#pragma unroll
        for (int ni = 0; ni < 4; ++ni) {
            const int col = n0 + wc * 64 + ni * 16 + (lane & 15);
#pragma unroll
            for (int r = 0; r < 4; ++r) {
                const int row = m0 + wr * 64 + mi * 16 + (lane >> 4) * 4 + r;
                float gv = accG[mi][ni][r];
                float uv = accU[mi][ni][r];
                float hv = (gv / (1.0f + __expf(-gv))) * uv;
                H[(size_t)row * I_DIM + col] = f2bf(hv);
            }
        }
}

__global__ __launch_bounds__(256, 2)
void gemm_down_fb(const unsigned short* __restrict__ Hr,
                  const int* __restrict__ Wd, const float* __restrict__ Sd,
                  float* __restrict__ Out)
{
    __shared__ __align__(16) unsigned short lA[128 * 64];
    __shared__ __align__(16) unsigned short lB[128 * 64];
    const int MT = T_DIM / 128;
    const int bid = blockIdx.x;
    const int m0 = (bid % MT) * 128;
    const int n0 = (bid / MT) * 128;
    const int tid  = threadIdx.x;
    const int lane = tid & 63;
    const int wid  = tid >> 6;
    const int wr = wid >> 1, wc = wid & 1;
    f32x4 acc[4][4];
#pragma unroll
    for (int i = 0; i < 4; ++i)
#pragma unroll
        for (int j = 0; j < 4; ++j) acc[i][j] = (f32x4)0.0f;
    const int arow = lane >> 3;
    const int acol = (lane & 7) * 8;
    const int SStride = I_DIM / GRP;
    for (int k0 = 0; k0 < I_DIM; k0 += 64) {
        __syncthreads();
#pragma unroll
        for (int it = 0; it < 4; ++it) {
            int chunk = wid * 4 + it;
            const unsigned short* gp = Hr + (size_t)(m0 + chunk * 8 + arow) * I_DIM + k0 + acol;
            __builtin_amdgcn_global_load_lds((gmem_void*)gp, (lds_void*)(lA + chunk * 512), 16, 0, 0);
        }
        const int g = k0 >> 7;
#pragma unroll
        for (int i = 0; i < 8; ++i) {
            int linear = i * 1024 + tid * 4;
            int r = linear >> 6;
            int c = linear & 63;
            const int32x4 wd = *reinterpret_cast<const int32x4*>(Wd + (size_t)(n0 + r) * I_DIM + k0 + c);
            float sc = Sd[(size_t)(n0 + r) * SStride + g];
            unsigned int d01 = (unsigned int)f2bf((float)(wd.x - 8) * sc) | ((unsigned int)f2bf((float)(wd.y - 8) * sc) << 16);
            unsigned int d23 = (unsigned int)f2bf((float)(wd.z - 8) * sc) | ((unsigned int)f2bf((float)(wd.w - 8) * sc) << 16);
            *reinterpret_cast<uint2*>(lB + r * 64 + c) = make_uint2(d01, d23);
        }
        __syncthreads();
#pragma unroll
        for (int ks = 0; ks < 2; ++ks) {
            const int koff = ks * 32 + (lane >> 4) * 8;
            bf16x8 af[4], bfr[4];
#pragma unroll
            for (int mi = 0; mi < 4; ++mi)
                af[mi] = *reinterpret_cast<const bf16x8*>(lA + (wr * 64 + mi * 16 + (lane & 15)) * 64 + koff);
#pragma unroll
            for (int ni = 0; ni < 4; ++ni)
                bfr[ni] = *reinterpret_cast<const bf16x8*>(lB + (wc * 64 + ni * 16 + (lane & 15)) * 64 + koff);
#pragma unroll
            for (int mi = 0; mi < 4; ++mi)
#pragma unroll
                for (int ni = 0; ni < 4; ++ni)
                    acc[mi][ni] = __builtin_amdgcn_mfma_f32_16x16x32_bf16(af[mi], bfr[ni], acc[mi][ni], 0, 0, 0);
        }
    }
#pragma unroll
    for (int mi = 0; mi < 4; ++mi)
#pragma unroll
        for (int ni = 0; ni < 4; ++ni) {
            const int col = n0 + wc * 64 + ni * 16 + (lane & 15);
#pragma unroll
            for (int r = 0; r < 4; ++r) {
                const int row = m0 + wr * 64 + mi * 16 + (lane >> 4) * 4 + r;
                Out[(size_t)row * D_DIM + col] = acc[mi][ni][r];
            }
        }
}

extern "C" void kernel_launch(void* const* d_in, const int* in_sizes, int n_in,
                              void* d_out, int out_size, void* d_ws, size_t ws_size,
                              hipStream_t stream) {
    const float* x       = (const float*)d_in[0];
    const int*   wq_gate = (const int*)d_in[1];
    const float* s_gate  = (const float*)d_in[2];
    const int*   wq_up   = (const int*)d_in[3];
    const float* s_up    = (const float*)d_in[4];
    const int*   wq_down = (const int*)d_in[5];
    const float* s_down  = (const float*)d_in[6];
    float* out = (float*)d_out;

    const size_t XR_E = (size_t)T_DIM * D_DIM;      // 16.8M
    const size_t H_E  = (size_t)T_DIM * I_DIM;      // 50.3M
    const size_t W_E  = (size_t)I_DIM * D_DIM;      // 50.3M
    const size_t need = (XR_E + H_E + 2 * W_E) * sizeof(unsigned short);  // 335.5 MB

    unsigned short* xr = (unsigned short*)d_ws;
    unsigned short* h  = xr + XR_E;

    // 1) xr = hadamard(x) -> bf16
    {
        int ngroups = (int)(XR_E / 128);
        had_f32_to_bf16<<<dim3(ngroups / 4), dim3(256), 0, stream>>>(x, xr, ngroups);
    }

    if (ws_size >= need) {
        unsigned short* wgbf = h + H_E;
        unsigned short* wubf = wgbf + W_E;
        int total8 = (int)(W_E / 8);
        // 2) pre-dequant gate & up weights -> bf16
        dequant_w<<<dim3((total8 + 255) / 256), dim3(256), 0, stream>>>(wq_gate, s_gate, wgbf, D_DIM, total8);
        dequant_w<<<dim3((total8 + 255) / 256), dim3(256), 0, stream>>>(wq_up,   s_up,   wubf, D_DIM, total8);
        // 3) gate = xr @ Wg^T  (bf16, into h)
        gemm256<0><<<dim3((T_DIM / 256) * (I_DIM / 256)), dim3(512), 0, stream>>>(
            xr, wgbf, (void*)h, T_DIM, I_DIM, D_DIM);
        // 4) h = silu(gate) * (xr @ Wu^T)   (fused epilogue, in place over h)
        gemm256<1><<<dim3((T_DIM / 256) * (I_DIM / 256)), dim3(512), 0, stream>>>(
            xr, wubf, (void*)h, T_DIM, I_DIM, D_DIM);
        // 5) h = hadamard(h) in place
        {
            int ngroups = (int)(H_E / 128);
            had_bf16_inplace<<<dim3(ngroups / 4), dim3(256), 0, stream>>>(h, ngroups);
        }
        // 6) dequant down weights (reuse gate buffer)
        dequant_w<<<dim3((total8 + 255) / 256), dim3(256), 0, stream>>>(wq_down, s_down, wgbf, I_DIM, total8);
        // 7) out = h @ Wd^T  (f32)
        gemm256<2><<<dim3((T_DIM / 256) * (D_DIM / 256)), dim3(512), 0, stream>>>(
            h, wgbf, (void*)out, T_DIM, D_DIM, I_DIM);
    } else {
        // fallback: round-1 verified path (in-loop dequant)
        gemm_gateup_fb<<<dim3((T_DIM / 128) * (I_DIM / 128)), dim3(256), 0, stream>>>(
            xr, wq_gate, s_gate, wq_up, s_up, h);
        {
            int ngroups = (int)(H_E / 128);
            had_bf16_inplace<<<dim3(ngroups / 4), dim3(256), 0, stream>>>(h, ngroups);
        }
        gemm_down_fb<<<dim3((T_DIM / 128) * (D_DIM / 128)), dim3(256), 0, stream>>>(
            h, wq_down, s_down, out);
    }
}

// Round 7
// 1290.991 us; speedup vs baseline: 1.9913x; 1.9913x over previous
//
#include <hip/hip_runtime.h>
#include <hip/hip_bf16.h>
#include <cstdint>

#define T_DIM 4096
#define D_DIM 4096
#define I_DIM 12288
#define GRP   128

typedef __attribute__((ext_vector_type(8))) short bf16x8;   // MFMA A/B frag (8 bf16)
typedef __attribute__((ext_vector_type(4))) float f32x4;    // MFMA C/D frag
typedef __attribute__((ext_vector_type(4))) int   int32x4;

typedef __attribute__((address_space(3))) void lds_void;
typedef const __attribute__((address_space(1))) void gmem_void;

// f32 -> bf16 bits, round-to-nearest-even (finite inputs)
static __device__ __forceinline__ unsigned short f2bf(float f) {
    unsigned int u = __float_as_uint(f);
    u += 0x7FFFu + ((u >> 16) & 1u);
    return (unsigned short)(u >> 16);
}
static __device__ __forceinline__ float bf2f(unsigned short b) {
    return __uint_as_float(((unsigned int)b) << 16);
}

// ---------------- Hadamard (blockwise-128 FWHT), one wave per group, 2 elems/lane ----
__global__ void had_f32_to_bf16(const float* __restrict__ in, unsigned short* __restrict__ out,
                                int ngroups) {
    int gid = blockIdx.x * (blockDim.x >> 6) + (threadIdx.x >> 6);
    if (gid >= ngroups) return;
    int lane = threadIdx.x & 63;
    const float2 v2 = *reinterpret_cast<const float2*>(in + (size_t)gid * 128 + lane * 2);
    float v0 = v2.x, v1 = v2.y;
    { float t0 = v0 + v1, t1 = v0 - v1; v0 = t0; v1 = t1; }
#pragma unroll
    for (int m = 1; m <= 32; m <<= 1) {
        float b0 = __shfl_xor(v0, m);
        float b1 = __shfl_xor(v1, m);
        if (lane & m) { v0 = b0 - v0; v1 = b1 - v1; }
        else          { v0 = v0 + b0; v1 = v1 + b1; }
    }
    const float s = 0.08838834764831843f;  // 1/sqrt(128)
    unsigned int o = (unsigned int)f2bf(v0 * s) | ((unsigned int)f2bf(v1 * s) << 16);
    *reinterpret_cast<unsigned int*>(out + (size_t)gid * 128 + lane * 2) = o;
}

__global__ void had_bf16_inplace(unsigned short* __restrict__ buf, int ngroups) {
    int gid = blockIdx.x * (blockDim.x >> 6) + (threadIdx.x >> 6);
    if (gid >= ngroups) return;
    int lane = threadIdx.x & 63;
    unsigned int pv = *reinterpret_cast<const unsigned int*>(buf + (size_t)gid * 128 + lane * 2);
    float v0 = __uint_as_float((pv & 0xFFFFu) << 16);
    float v1 = __uint_as_float(pv & 0xFFFF0000u);
    { float t0 = v0 + v1, t1 = v0 - v1; v0 = t0; v1 = t1; }
#pragma unroll
    for (int m = 1; m <= 32; m <<= 1) {
        float b0 = __shfl_xor(v0, m);
        float b1 = __shfl_xor(v1, m);
        if (lane & m) { v0 = b0 - v0; v1 = b1 - v1; }
        else          { v0 = v0 + b0; v1 = v1 + b1; }
    }
    const float s = 0.08838834764831843f;
    unsigned int o = (unsigned int)f2bf(v0 * s) | ((unsigned int)f2bf(v1 * s) << 16);
    *reinterpret_cast<unsigned int*>(buf + (size_t)gid * 128 + lane * 2) = o;
}

// ---------------- weight dequant: int4-in-int32 [O,In] -> bf16 [O,In] ----------------
__global__ void dequant_w(const int* __restrict__ Wq, const float* __restrict__ S,
                          unsigned short* __restrict__ Wbf, int In, int total8) {
    int t = blockIdx.x * blockDim.x + threadIdx.x;
    if (t >= total8) return;
    size_t base = (size_t)t * 8;
    size_t row = base / (size_t)In;
    int col = (int)(base - row * (size_t)In);
    float sc = S[row * (size_t)(In >> 7) + (col >> 7)];
    const int32x4* p = reinterpret_cast<const int32x4*>(Wq + base);
    int32x4 a = p[0], b = p[1];
    float nsc = -8.0f * sc;
    unsigned int o0 = (unsigned int)f2bf((float)a.x * sc + nsc) |
                      ((unsigned int)f2bf((float)a.y * sc + nsc) << 16);
    unsigned int o1 = (unsigned int)f2bf((float)a.z * sc + nsc) |
                      ((unsigned int)f2bf((float)a.w * sc + nsc) << 16);
    unsigned int o2 = (unsigned int)f2bf((float)b.x * sc + nsc) |
                      ((unsigned int)f2bf((float)b.y * sc + nsc) << 16);
    unsigned int o3 = (unsigned int)f2bf((float)b.z * sc + nsc) |
                      ((unsigned int)f2bf((float)b.w * sc + nsc) << 16);
    *reinterpret_cast<uint4*>(Wbf + base) = make_uint4(o0, o1, o2, o3);
}

// =====================================================================================
// 256x256 GEMM = K4 (verified best) + loop-invariant address hoisting.
// 2 K-tiles/iter, 8 phases, 2 LDS buffers (128 KB), M/N-half staging, vmcnt(4) at
// ph4/ph8, 2 barriers/phase, explicit lgkm0 before MFMA cluster, setprio around MFMA.
// C[M,N] = A[M,K] @ W[N,K]^T, bf16 in. MODE 0: bf16 out; 1: silu(C)*acc in place; 2: f32.
// 8 waves (2M x 4N); per-wave 128x64; per phase one m-quadrant (2m x 4n frags) x K=64.
// LDS buf: A[256][64] + B[256][64] bf16; row=128B=8 chunks; chunk c stores global
// chunk c^(row&7) (T2, source-side pre-swizzle for linear global_load_lds dest).
// HOISTING: frag-read addrs = 4 precomputed byte-bases + compile-time offsets;
// stage addrs = 2 global base ptrs + uniform strides; lds dests = 1 base + constants.
// =====================================================================================

#define GBAR()  __builtin_amdgcn_s_barrier()
#define LGKM0() asm volatile("s_waitcnt lgkmcnt(0)" ::: "memory")
#define VMW(n)  asm volatile("s_waitcnt vmcnt(" #n ")" ::: "memory")
#define P1()    __builtin_amdgcn_s_setprio(1)
#define P0()    __builtin_amdgcn_s_setprio(0)

// stage half-tile: buffer bb, mat (0=A,1=B), M-half h, k-base kb. 2 x global_load_lds.
#define STG(bb, mat, h, kb)                                                            \
  { _Pragma("unroll")                                                                  \
    for (int i_ = 0; i_ < 2; ++i_) {                                                   \
      const unsigned short* gp_ = ((mat) ? gW : gA)                                    \
          + (size_t)((h) * 128 + i_ * 64) * K + (kb);                                  \
      unsigned short* lp_ = lds_stg + (bb) * 32768 + (mat) * 16384                     \
          + ((h) * 128 + i_ * 64) * 64;                                                \
      __builtin_amdgcn_global_load_lds((gmem_void*)gp_, (lds_void*)lp_, 16, 0, 0);     \
    } }

// per-phase A frags: quadrant q (2 m-frags x 2 k-subs); base + compile-time offsets
#define LDA(bb, q)                                                                     \
  af[0][0] = *reinterpret_cast<const bf16x8*>(aB0 + (bb) * 65536 + ((q) * 2 + 0) * 2048); \
  af[0][1] = *reinterpret_cast<const bf16x8*>(aB1 + (bb) * 65536 + ((q) * 2 + 0) * 2048); \
  af[1][0] = *reinterpret_cast<const bf16x8*>(aB0 + (bb) * 65536 + ((q) * 2 + 1) * 2048); \
  af[1][1] = *reinterpret_cast<const bf16x8*>(aB1 + (bb) * 65536 + ((q) * 2 + 1) * 2048);

// per-K-tile B frags: 4 n-frags x 2 k-subs (live across 4 phases)
#define LDB(bb)                                                                        \
  _Pragma("unroll")                                                                    \
  for (int ni_ = 0; ni_ < 4; ++ni_) {                                                  \
    bk[ni_][0] = *reinterpret_cast<const bf16x8*>(bB0 + (bb) * 65536 + ni_ * 2048);    \
    bk[ni_][1] = *reinterpret_cast<const bf16x8*>(bB1 + (bb) * 65536 + ni_ * 2048);    \
  }

#define MF16(q)                                                                        \
  _Pragma("unroll")                                                                    \
  for (int ks_ = 0; ks_ < 2; ++ks_)                                                    \
  _Pragma("unroll")                                                                    \
  for (int mi_ = 0; mi_ < 2; ++mi_)                                                    \
  _Pragma("unroll")                                                                    \
  for (int ni_ = 0; ni_ < 4; ++ni_)                                                    \
    acc[(q) * 2 + mi_][ni_] = __builtin_amdgcn_mfma_f32_16x16x32_bf16(                 \
        af[mi_][ks_], bk[ni_][ks_], acc[(q) * 2 + mi_][ni_], 0, 0, 0);

template<int MODE>
__global__ __launch_bounds__(512, 2)
void gemm256(const unsigned short* __restrict__ A,      // [M,K] bf16
             const unsigned short* __restrict__ W,      // [N,K] bf16
             void* __restrict__ C, int M, int N, int K)
{
    __shared__ __align__(16) unsigned short lds[65536];  // 128 KB

    const int MT = M >> 8;
    const int nwg = gridDim.x;
    const int bid = blockIdx.x;
    const int cpx = nwg >> 3;                     // nwg % 8 == 0 in all our launches
    const int wg  = (bid & 7) * cpx + (bid >> 3); // bijective XCD swizzle
    const int m0 = (wg % MT) << 8;
    const int n0 = (wg / MT) << 8;

    const int tid  = threadIdx.x;
    const int lane = tid & 63;
    const int wid  = tid >> 6;
    const int wr = wid >> 2;                      // 0..1 (M half)
    const int wc = wid & 3;                       // 0..3 (N quarter)
    const int kc = lane >> 4;                     // 16B k-chunk selector
    const int lane7 = lane & 7;

    // ---- hoisted LDS frag-read byte bases (buffer 0; +65536 B for buffer 1) ----
    const char* ldsb = (const char*)lds;
    const int thrA = (wr * 128 + (lane & 15)) * 128;
    const int thrB = 32768 + (wc * 64 + (lane & 15)) * 128;
    const int xo0 = ((0 + kc) ^ lane7) * 16;      // k-sub 0: chunk kc
    const int xo1 = ((4 + kc) ^ lane7) * 16;      // k-sub 1: chunk 4+kc
    const char* aB0 = ldsb + thrA + xo0;
    const char* aB1 = ldsb + thrA + xo1;
    const char* bB0 = ldsb + thrB + xo0;
    const char* bB1 = ldsb + thrB + xo1;

    // ---- hoisted stage bases: per-thread row + source-side swizzle ----
    const int srow = tid >> 3;                    // 0..63
    const int sswz = ((tid & 7) ^ (srow & 7)) * 8;
    const unsigned short* gA = A + (size_t)(m0 + srow) * K + sswz;
    const unsigned short* gW = W + (size_t)(n0 + srow) * K + sswz;
    unsigned short* lds_stg = lds + (size_t)(wid * 8) * 64;

    f32x4 acc[8][4];
#pragma unroll
    for (int i = 0; i < 8; ++i)
#pragma unroll
        for (int j = 0; j < 4; ++j) acc[i][j] = (f32x4)0.0f;

    const int NT = K >> 6;                        // K-tiles (even: 64 or 192)
    const int J  = NT >> 1;                       // iterations

    // ---- prologue: tile0 (A+B) and tile1 (B); retire tile0, keep B(1) in flight ----
    STG(0, 0, 0, 0); STG(0, 0, 1, 0); STG(0, 1, 0, 0); STG(0, 1, 1, 0);
    STG(1, 1, 0, 64); STG(1, 1, 1, 64);
    VMW(4);
    GBAR();

    bf16x8 af[2][2], bk[4][2];

    for (int j = 0; j < J - 1; ++j) {
        const int ka  = (j << 7);           // tile a = 2j     (buf0)
        const int kb1 = ka + 64;            // tile a+1        (buf1)
        const int ka2 = ka + 128;           // tile a+2
        const int ka3 = ka + 192;           // tile a+3
        // ---- ph1: tile a, q0 ----
        LDB(0); LDA(0, 0); STG(1, 0, 0, kb1);
        GBAR(); LGKM0(); P1(); MF16(0); P0(); GBAR();
        // ---- ph2: q1 ----
        LDA(0, 1); STG(1, 0, 1, kb1);
        GBAR(); LGKM0(); P1(); MF16(1); P0(); GBAR();
        // ---- ph3: q2 ----
        LDA(0, 2); STG(0, 1, 0, ka2);
        GBAR(); LGKM0(); P1(); MF16(2); P0(); GBAR();
        // ---- ph4: q3 ----
        LDA(0, 3); STG(0, 1, 1, ka2);
        GBAR(); LGKM0(); P1(); MF16(3); P0(); VMW(4); GBAR();
        // ---- ph5: tile a+1, q0 ----
        LDB(1); LDA(1, 0); STG(0, 0, 0, ka2);
        GBAR(); LGKM0(); P1(); MF16(0); P0(); GBAR();
        // ---- ph6: q1 ----
        LDA(1, 1); STG(0, 0, 1, ka2);
        GBAR(); LGKM0(); P1(); MF16(1); P0(); GBAR();
        // ---- ph7: q2 ----
        LDA(1, 2); STG(1, 1, 0, ka3);
        GBAR(); LGKM0(); P1(); MF16(2); P0(); GBAR();
        // ---- ph8: q3 ----
        LDA(1, 3); STG(1, 1, 1, ka3);
        GBAR(); LGKM0(); P1(); MF16(3); P0(); VMW(4); GBAR();
    }

    // ---- peeled final iteration (tiles NT-2, NT-1): stage only A(NT-1) ----
    {
        const int kb1 = ((NT - 1) << 6);
        LDB(0); LDA(0, 0); STG(1, 0, 0, kb1);
        GBAR(); LGKM0(); P1(); MF16(0); P0(); GBAR();
        LDA(0, 1); STG(1, 0, 1, kb1);
        GBAR(); LGKM0(); P1(); MF16(1); P0(); GBAR();
        LDA(0, 2);
        GBAR(); LGKM0(); P1(); MF16(2); P0(); GBAR();
        LDA(0, 3);
        GBAR(); LGKM0(); P1(); MF16(3); P0(); VMW(0); GBAR();
        LDB(1); LDA(1, 0);
        GBAR(); LGKM0(); P1(); MF16(0); P0(); GBAR();
        LDA(1, 1);
        GBAR(); LGKM0(); P1(); MF16(1); P0(); GBAR();
        LDA(1, 2);
        GBAR(); LGKM0(); P1(); MF16(2); P0(); GBAR();
        LDA(1, 3);
        GBAR(); LGKM0(); P1(); MF16(3); P0(); GBAR();
    }

    // ---- epilogue ----
#pragma unroll
    for (int mi = 0; mi < 8; ++mi)
#pragma unroll
        for (int ni = 0; ni < 4; ++ni) {
            const int col = n0 + (wc << 6) + ni * 16 + (lane & 15);
#pragma unroll
            for (int r = 0; r < 4; ++r) {
                const int row = m0 + (wr << 7) + mi * 16 + ((lane >> 4) << 2) + r;
                const size_t idx = (size_t)row * N + col;
                if (MODE == 2) {
                    ((float*)C)[idx] = acc[mi][ni][r];
                } else if (MODE == 0) {
                    ((unsigned short*)C)[idx] = f2bf(acc[mi][ni][r]);
                } else {
                    float g = bf2f(((unsigned short*)C)[idx]);
                    float u = acc[mi][ni][r];
                    float h = (g / (1.0f + __expf(-g))) * u;
                    ((unsigned short*)C)[idx] = f2bf(h);
                }
            }
        }
}

// ================== FALLBACK (round-1 verified): in-loop dequant GEMMs ==============
__global__ __launch_bounds__(256, 2)
void gemm_gateup_fb(const unsigned short* __restrict__ Xr,
                    const int* __restrict__ Wg, const float* __restrict__ Sg,
                    const int* __restrict__ Wu, const float* __restrict__ Su,
                    unsigned short* __restrict__ H)
{
    __shared__ __align__(16) unsigned short lA [128 * 64];
    __shared__ __align__(16) unsigned short lBg[128 * 64];
    __shared__ __align__(16) unsigned short lBu[128 * 64];
    const int MT = T_DIM / 128;
    const int bid = blockIdx.x;
    const int m0 = (bid % MT) * 128;
    const int n0 = (bid / MT) * 128;
    const int tid  = threadIdx.x;
    const int lane = tid & 63;
    const int wid  = tid >> 6;
    const int wr = wid >> 1, wc = wid & 1;
    f32x4 accG[4][4], accU[4][4];
#pragma unroll
    for (int i = 0; i < 4; ++i)
#pragma unroll
        for (int j = 0; j < 4; ++j) { accG[i][j] = (f32x4)0.0f; accU[i][j] = (f32x4)0.0f; }
    const int arow = lane >> 3;
    const int acol = (lane & 7) * 8;
    const int SStride = D_DIM / GRP;
    for (int k0 = 0; k0 < D_DIM; k0 += 64) {
        __syncthreads();
#pragma unroll
        for (int it = 0; it < 4; ++it) {
            int chunk = wid * 4 + it;
            const unsigned short* gp = Xr + (size_t)(m0 + chunk * 8 + arow) * D_DIM + k0 + acol;
            __builtin_amdgcn_global_load_lds((gmem_void*)gp, (lds_void*)(lA + chunk * 512), 16, 0, 0);
        }
        const int g = k0 >> 7;
#pragma unroll
        for (int i = 0; i < 8; ++i) {
            int linear = i * 1024 + tid * 4;
            int r = linear >> 6;
            int c = linear & 63;
            const int32x4 wg = *reinterpret_cast<const int32x4*>(Wg + (size_t)(n0 + r) * D_DIM + k0 + c);
            const int32x4 wu = *reinterpret_cast<const int32x4*>(Wu + (size_t)(n0 + r) * D_DIM + k0 + c);
            float scg = Sg[(size_t)(n0 + r) * SStride + g];
            float scu = Su[(size_t)(n0 + r) * SStride + g];
            unsigned int g01 = (unsigned int)f2bf((float)(wg.x - 8) * scg) | ((unsigned int)f2bf((float)(wg.y - 8) * scg) << 16);
            unsigned int g23 = (unsigned int)f2bf((float)(wg.z - 8) * scg) | ((unsigned int)f2bf((float)(wg.w - 8) * scg) << 16);
            unsigned int u01 = (unsigned int)f2bf((float)(wu.x - 8) * scu) | ((unsigned int)f2bf((float)(wu.y - 8) * scu) << 16);
            unsigned int u23 = (unsigned int)f2bf((float)(wu.z - 8) * scu) | ((unsigned int)f2bf((float)(wu.w - 8) * scu) << 16);
            *reinterpret_cast<uint2*>(lBg + r * 64 + c) = make_uint2(g01, g23);
            *reinterpret_cast<uint2*>(lBu + r * 64 + c) = make_uint2(u01, u23);
        }
        __syncthreads();
#pragma unroll
        for (int ks = 0; ks < 2; ++ks) {
            const int koff = ks * 32 + (lane >> 4) * 8;
            bf16x8 af[4], bg[4], bu[4];
#pragma unroll
            for (int mi = 0; mi < 4; ++mi)
                af[mi] = *reinterpret_cast<const bf16x8*>(lA + (wr * 64 + mi * 16 + (lane & 15)) * 64 + koff);
#pragma unroll
            for (int ni = 0; ni < 4; ++ni) {
                bg[ni] = *reinterpret_cast<const bf16x8*>(lBg + (wc * 64 + ni * 16 + (lane & 15)) * 64 + koff);
                bu[ni] = *reinterpret_cast<const bf16x8*>(lBu + (wc * 64 + ni * 16 + (lane & 15)) * 64 + koff);
            }
#pragma unroll
            for (int mi = 0; mi < 4; ++mi)
#pragma unroll
                for (int ni = 0; ni < 4; ++ni) {
                    accG[mi][ni] = __builtin_amdgcn_mfma_f32_16x16x32_bf16(af[mi], bg[ni], accG[mi][ni], 0, 0, 0);
                    accU[mi][ni] = __builtin_amdgcn_mfma_f32_16x16x32_bf16(af[mi], bu[ni], accU[mi][ni], 0, 0, 0);
                }
        }
    }
#pragma unroll
    for (int mi = 0; mi < 4; ++mi)
#pragma unroll
        for (int ni = 0; ni < 4; ++ni) {
            const int col = n0 + wc * 64 + ni * 16 + (lane & 15);
#pragma unroll
            for (int r = 0; r < 4; ++r) {
                const int row = m0 + wr * 64 + mi * 16 + (lane >> 4) * 4 + r;
                float gv = accG[mi][ni][r];
                float uv = accU[mi][ni][r];
                float hv = (gv / (1.0f + __expf(-gv))) * uv;
                H[(size_t)row * I_DIM + col] = f2bf(hv);
            }
        }
}

__global__ __launch_bounds__(256, 2)
void gemm_down_fb(const unsigned short* __restrict__ Hr,
                  const int* __restrict__ Wd, const float* __restrict__ Sd,
                  float* __restrict__ Out)
{
    __shared__ __align__(16) unsigned short lA[128 * 64];
    __shared__ __align__(16) unsigned short lB[128 * 64];
    const int MT = T_DIM / 128;
    const int bid = blockIdx.x;
    const int m0 = (bid % MT) * 128;
    const int n0 = (bid / MT) * 128;
    const int tid  = threadIdx.x;
    const int lane = tid & 63;
    const int wid  = tid >> 6;
    const int wr = wid >> 1, wc = wid & 1;
    f32x4 acc[4][4];
#pragma unroll
    for (int i = 0; i < 4; ++i)
#pragma unroll
        for (int j = 0; j < 4; ++j) acc[i][j] = (f32x4)0.0f;
    const int arow = lane >> 3;
    const int acol = (lane & 7) * 8;
    const int SStride = I_DIM / GRP;
    for (int k0 = 0; k0 < I_DIM; k0 += 64) {
        __syncthreads();
#pragma unroll
        for (int it = 0; it < 4; ++it) {
            int chunk = wid * 4 + it;
            const unsigned short* gp = Hr + (size_t)(m0 + chunk * 8 + arow) * I_DIM + k0 + acol;
            __builtin_amdgcn_global_load_lds((gmem_void*)gp, (lds_void*)(lA + chunk * 512), 16, 0, 0);
        }
        const int g = k0 >> 7;
#pragma unroll
        for (int i = 0; i < 8; ++i) {
            int linear = i * 1024 + tid * 4;
            int r = linear >> 6;
            int c = linear & 63;
            const int32x4 wd = *reinterpret_cast<const int32x4*>(Wd + (size_t)(n0 + r) * I_DIM + k0 + c);
            float sc = Sd[(size_t)(n0 + r) * SStride + g];
            unsigned int d01 = (unsigned int)f2bf((float)(wd.x - 8) * sc) | ((unsigned int)f2bf((float)(wd.y - 8) * sc) << 16);
            unsigned int d23 = (unsigned int)f2bf((float)(wd.z - 8) * sc) | ((unsigned int)f2bf((float)(wd.w - 8) * sc) << 16);
            *reinterpret_cast<uint2*>(lB + r * 64 + c) = make_uint2(d01, d23);
        }
        __syncthreads();
#pragma unroll
        for (int ks = 0; ks < 2; ++ks) {
            const int koff = ks * 32 + (lane >> 4) * 8;
            bf16x8 af[4], bfr[4];
#pragma unroll
            for (int mi = 0; mi < 4; ++mi)
                af[mi] = *reinterpret_cast<const bf16x8*>(lA + (wr * 64 + mi * 16 + (lane & 15)) * 64 + koff);
#pragma unroll
            for (int ni = 0; ni < 4; ++ni)
                bfr[ni] = *reinterpret_cast<const bf16x8*>(lB + (wc * 64 + ni * 16 + (lane & 15)) * 64 + koff);
#pragma unroll
            for (int mi = 0; mi < 4; ++mi)
#pragma unroll
                for (int ni = 0; ni < 4; ++ni)
                    acc[mi][ni] = __builtin_amdgcn_mfma_f32_16x16x32_bf16(af[mi], bfr[ni], acc[mi][ni], 0, 0, 0);
        }
    }
#pragma unroll
    for (int mi = 0; mi < 4; ++mi)
#pragma unroll
        for (int ni = 0; ni < 4; ++ni) {
            const int col = n0 + wc * 64 + ni * 16 + (lane & 15);
#pragma unroll
            for (int r = 0; r < 4; ++r) {
                const int row = m0 + wr * 64 + mi * 16 + (lane >> 4) * 4 + r;
                Out[(size_t)row * D_DIM + col] = acc[mi][ni][r];
            }
        }
}

extern "C" void kernel_launch(void* const* d_in, const int* in_sizes, int n_in,
                              void* d_out, int out_size, void* d_ws, size_t ws_size,
                              hipStream_t stream) {
    const float* x       = (const float*)d_in[0];
    const int*   wq_gate = (const int*)d_in[1];
    const float* s_gate  = (const float*)d_in[2];
    const int*   wq_up   = (const int*)d_in[3];
    const float* s_up    = (const float*)d_in[4];
    const int*   wq_down = (const int*)d_in[5];
    const float* s_down  = (const float*)d_in[6];
    float* out = (float*)d_out;

    const size_t XR_E = (size_t)T_DIM * D_DIM;      // 16.8M
    const size_t H_E  = (size_t)T_DIM * I_DIM;      // 50.3M
    const size_t W_E  = (size_t)I_DIM * D_DIM;      // 50.3M
    const size_t need = (XR_E + H_E + 2 * W_E) * sizeof(unsigned short);  // 335.5 MB

    unsigned short* xr = (unsigned short*)d_ws;
    unsigned short* h  = xr + XR_E;

    // 1) xr = hadamard(x) -> bf16
    {
        int ngroups = (int)(XR_E / 128);
        had_f32_to_bf16<<<dim3(ngroups / 4), dim3(256), 0, stream>>>(x, xr, ngroups);
    }

    if (ws_size >= need) {
        unsigned short* wgbf = h + H_E;
        unsigned short* wubf = wgbf + W_E;
        int total8 = (int)(W_E / 8);
        // 2) pre-dequant gate & up weights -> bf16
        dequant_w<<<dim3((total8 + 255) / 256), dim3(256), 0, stream>>>(wq_gate, s_gate, wgbf, D_DIM, total8);
        dequant_w<<<dim3((total8 + 255) / 256), dim3(256), 0, stream>>>(wq_up,   s_up,   wubf, D_DIM, total8);
        // 3) gate = xr @ Wg^T  (bf16, into h)
        gemm256<0><<<dim3((T_DIM / 256) * (I_DIM / 256)), dim3(512), 0, stream>>>(
            xr, wgbf, (void*)h, T_DIM, I_DIM, D_DIM);
        // 4) h = silu(gate) * (xr @ Wu^T)   (fused epilogue, in place over h)
        gemm256<1><<<dim3((T_DIM / 256) * (I_DIM / 256)), dim3(512), 0, stream>>>(
            xr, wubf, (void*)h, T_DIM, I_DIM, D_DIM);
        // 5) h = hadamard(h) in place
        {
            int ngroups = (int)(H_E / 128);
            had_bf16_inplace<<<dim3(ngroups / 4), dim3(256), 0, stream>>>(h, ngroups);
        }
        // 6) dequant down weights (reuse gate buffer)
        dequant_w<<<dim3((total8 + 255) / 256), dim3(256), 0, stream>>>(wq_down, s_down, wgbf, I_DIM, total8);
        // 7) out = h @ Wd^T  (f32)
        gemm256<2><<<dim3((T_DIM / 256) * (D_DIM / 256)), dim3(512), 0, stream>>>(
            h, wgbf, (void*)out, T_DIM, D_DIM, I_DIM);
    } else {
        // fallback: round-1 verified path (in-loop dequant)
        gemm_gateup_fb<<<dim3((T_DIM / 128) * (I_DIM / 128)), dim3(256), 0, stream>>>(
            xr, wq_gate, s_gate, wq_up, s_up, h);
        {
            int ngroups = (int)(H_E / 128);
            had_bf16_inplace<<<dim3(ngroups / 4), dim3(256), 0, stream>>>(h, ngroups);
        }
        gemm_down_fb<<<dim3((T_DIM / 128) * (D_DIM / 128)), dim3(256), 0, stream>>>(
            h, wq_down, s_down, out);
    }
}

// Round 10
// 1278.088 us; speedup vs baseline: 2.0114x; 1.0101x over previous
//
#include <hip/hip_runtime.h>
#include <hip/hip_bf16.h>
#include <cstdint>

#define T_DIM 4096
#define D_DIM 4096
#define I_DIM 12288
#define GRP   128

typedef __attribute__((ext_vector_type(8))) short bf16x8;   // MFMA A/B frag (8 bf16)
typedef __attribute__((ext_vector_type(4))) float f32x4;    // MFMA C/D frag
typedef __attribute__((ext_vector_type(4))) int   int32x4;

typedef __attribute__((address_space(3))) void lds_void;
typedef const __attribute__((address_space(1))) void gmem_void;

// f32 -> bf16 bits, round-to-nearest-even (finite inputs)
static __device__ __forceinline__ unsigned short f2bf(float f) {
    unsigned int u = __float_as_uint(f);
    u += 0x7FFFu + ((u >> 16) & 1u);
    return (unsigned short)(u >> 16);
}
static __device__ __forceinline__ float bf2f(unsigned short b) {
    return __uint_as_float(((unsigned int)b) << 16);
}

// ---------------- Hadamard (blockwise-128 FWHT), one wave per group, 2 elems/lane ----
__global__ void had_f32_to_bf16(const float* __restrict__ in, unsigned short* __restrict__ out,
                                int ngroups) {
    int gid = blockIdx.x * (blockDim.x >> 6) + (threadIdx.x >> 6);
    if (gid >= ngroups) return;
    int lane = threadIdx.x & 63;
    const float2 v2 = *reinterpret_cast<const float2*>(in + (size_t)gid * 128 + lane * 2);
    float v0 = v2.x, v1 = v2.y;
    { float t0 = v0 + v1, t1 = v0 - v1; v0 = t0; v1 = t1; }
#pragma unroll
    for (int m = 1; m <= 32; m <<= 1) {
        float b0 = __shfl_xor(v0, m);
        float b1 = __shfl_xor(v1, m);
        if (lane & m) { v0 = b0 - v0; v1 = b1 - v1; }
        else          { v0 = v0 + b0; v1 = v1 + b1; }
    }
    const float s = 0.08838834764831843f;  // 1/sqrt(128)
    unsigned int o = (unsigned int)f2bf(v0 * s) | ((unsigned int)f2bf(v1 * s) << 16);
    *reinterpret_cast<unsigned int*>(out + (size_t)gid * 128 + lane * 2) = o;
}

__global__ void had_bf16_inplace(unsigned short* __restrict__ buf, int ngroups) {
    int gid = blockIdx.x * (blockDim.x >> 6) + (threadIdx.x >> 6);
    if (gid >= ngroups) return;
    int lane = threadIdx.x & 63;
    unsigned int pv = *reinterpret_cast<const unsigned int*>(buf + (size_t)gid * 128 + lane * 2);
    float v0 = __uint_as_float((pv & 0xFFFFu) << 16);
    float v1 = __uint_as_float(pv & 0xFFFF0000u);
    { float t0 = v0 + v1, t1 = v0 - v1; v0 = t0; v1 = t1; }
#pragma unroll
    for (int m = 1; m <= 32; m <<= 1) {
        float b0 = __shfl_xor(v0, m);
        float b1 = __shfl_xor(v1, m);
        if (lane & m) { v0 = b0 - v0; v1 = b1 - v1; }
        else          { v0 = v0 + b0; v1 = v1 + b1; }
    }
    const float s = 0.08838834764831843f;
    unsigned int o = (unsigned int)f2bf(v0 * s) | ((unsigned int)f2bf(v1 * s) << 16);
    *reinterpret_cast<unsigned int*>(buf + (size_t)gid * 128 + lane * 2) = o;
}

// ---------------- weight dequant: int4-in-int32 [O,In] -> bf16 [O,In] ----------------
__global__ void dequant_w(const int* __restrict__ Wq, const float* __restrict__ S,
                          unsigned short* __restrict__ Wbf, int In, int total8) {
    int t = blockIdx.x * blockDim.x + threadIdx.x;
    if (t >= total8) return;
    size_t base = (size_t)t * 8;
    size_t row = base / (size_t)In;
    int col = (int)(base - row * (size_t)In);
    float sc = S[row * (size_t)(In >> 7) + (col >> 7)];
    const int32x4* p = reinterpret_cast<const int32x4*>(Wq + base);
    int32x4 a = p[0], b = p[1];
    float nsc = -8.0f * sc;
    unsigned int o0 = (unsigned int)f2bf((float)a.x * sc + nsc) |
                      ((unsigned int)f2bf((float)a.y * sc + nsc) << 16);
    unsigned int o1 = (unsigned int)f2bf((float)a.z * sc + nsc) |
                      ((unsigned int)f2bf((float)a.w * sc + nsc) << 16);
    unsigned int o2 = (unsigned int)f2bf((float)b.x * sc + nsc) |
                      ((unsigned int)f2bf((float)b.y * sc + nsc) << 16);
    unsigned int o3 = (unsigned int)f2bf((float)b.z * sc + nsc) |
                      ((unsigned int)f2bf((float)b.w * sc + nsc) << 16);
    *reinterpret_cast<uint4*>(Wbf + base) = make_uint4(o0, o1, o2, o3);
}

// =====================================================================================
// 256x256 GEMM = r4 skeleton + A-frag ping-pong pipeline.
// Phase p issues the ds_reads for phase p+1's A-quadrant BEFORE p's MFMA cluster, so
// the LDS pipe drains during the matrix-pipe cluster instead of serializing with it.
// B frags (bk) single-buffered: LDB at ph1/ph5, same-phase use (one drain per 4 phases).
// vmcnt ledger (hand-verified steady state): VMW(2) at ph4/ph8 ENTRY, before the
// cross-buffer LDA; entry outstanding = 10 loads, retires the 8 oldest.
// C[M,N] = A[M,K] @ W[N,K]^T, bf16 in. MODE 0: bf16 out; 1: silu(C)*acc in place; 2: f32.
// 8 waves (2M x 4N); per-wave 128x64; per phase one m-quadrant (2m x 4n frags) x K=64.
// LDS buf (x2): A[256][64] + B[256][64] bf16; chunk c stores global chunk c^(row&7) (T2).
// NO manual lgkmcnt: compiler emits dependency-exact counts for C++ LDS loads.
// =====================================================================================

#define GBAR()  __builtin_amdgcn_s_barrier()
#define VMW(n)  asm volatile("s_waitcnt vmcnt(" #n ")" ::: "memory")
#define P1()    __builtin_amdgcn_s_setprio(1)
#define P0()    __builtin_amdgcn_s_setprio(0)

// stage half-tile: buffer bb, mat (0=A,1=B), M-half h, k-base kb. 2 x global_load_lds.
#define STG(bb, mat, h, kb)                                                            \
  { _Pragma("unroll")                                                                  \
    for (int i_ = 0; i_ < 2; ++i_) {                                                   \
      const int rl_ = (h) * 128 + i_ * 64 + (tid >> 3);                                \
      const int gs_ = (tid & 7) ^ ((tid >> 3) & 7);                                    \
      const unsigned short* gp_ = ((mat) ? W : A) +                                    \
          (size_t)(((mat) ? n0 : m0) + rl_) * K + (kb) + gs_ * 8;                      \
      unsigned short* lp_ = lds + (bb) * 32768 + (mat) * 16384 +                       \
          ((h) * 128 + i_ * 64 + wid * 8) * 64;                                        \
      __builtin_amdgcn_global_load_lds((gmem_void*)gp_, (lds_void*)lp_, 16, 0, 0);     \
    } }

// read A frags for m-quadrant q of buffer bb into dst[2][2]
#define LDAQ(dst, bb, q)                                                               \
  _Pragma("unroll")                                                                    \
  for (int mi_ = 0; mi_ < 2; ++mi_)                                                    \
  _Pragma("unroll")                                                                    \
  for (int ks_ = 0; ks_ < 2; ++ks_) {                                                  \
    int r_ = wr * 128 + (q) * 32 + mi_ * 16 + (lane & 15);                             \
    int c_ = ks_ * 4 + kc;                                                             \
    dst[mi_][ks_] = *reinterpret_cast<const bf16x8*>(                                  \
        lds + (bb) * 32768 + r_ * 64 + ((c_ ^ (r_ & 7)) << 3));                        \
  }

// read B frags (full K-tile) of buffer bb into bk[4][2]
#define LDBQ(bb)                                                                       \
  _Pragma("unroll")                                                                    \
  for (int ni_ = 0; ni_ < 4; ++ni_)                                                    \
  _Pragma("unroll")                                                                    \
  for (int ks_ = 0; ks_ < 2; ++ks_) {                                                  \
    int r_ = wc * 64 + ni_ * 16 + (lane & 15);                                         \
    int c_ = ks_ * 4 + kc;                                                             \
    bk[ni_][ks_] = *reinterpret_cast<const bf16x8*>(                                   \
        lds + (bb) * 32768 + 16384 + r_ * 64 + ((c_ ^ (r_ & 7)) << 3));                \
  }

#define MF16(q, afb)                                                                   \
  _Pragma("unroll")                                                                    \
  for (int ks_ = 0; ks_ < 2; ++ks_)                                                    \
  _Pragma("unroll")                                                                    \
  for (int mi_ = 0; mi_ < 2; ++mi_)                                                    \
  _Pragma("unroll")                                                                    \
  for (int ni_ = 0; ni_ < 4; ++ni_)                                                    \
    acc[(q) * 2 + mi_][ni_] = __builtin_amdgcn_mfma_f32_16x16x32_bf16(                 \
        afb[mi_][ks_], bk[ni_][ks_], acc[(q) * 2 + mi_][ni_], 0, 0, 0);

template<int MODE>
__global__ __launch_bounds__(512, 2)
void gemm256(const unsigned short* __restrict__ A,      // [M,K] bf16
             const unsigned short* __restrict__ W,      // [N,K] bf16
             void* __restrict__ C, int M, int N, int K)
{
    __shared__ __align__(16) unsigned short lds[65536];  // 128 KB

    const int MT = M >> 8;
    const int nwg = gridDim.x;
    const int bid = blockIdx.x;
    const int cpx = nwg >> 3;                     // nwg % 8 == 0 in all our launches
    const int wg  = (bid & 7) * cpx + (bid >> 3); // bijective XCD swizzle
    const int m0 = (wg % MT) << 8;
    const int n0 = (wg / MT) << 8;

    const int tid  = threadIdx.x;
    const int lane = tid & 63;
    const int wid  = tid >> 6;
    const int wr = wid >> 2;                      // 0..1 (M half)
    const int wc = wid & 3;                       // 0..3 (N quarter)
    const int kc = lane >> 4;                     // 16B k-chunk selector

    f32x4 acc[8][4];
#pragma unroll
    for (int i = 0; i < 8; ++i)
#pragma unroll
        for (int j = 0; j < 4; ++j) acc[i][j] = (f32x4)0.0f;

    const int NT = K >> 6;                        // K-tiles (even: 64 or 192)
    const int J  = NT >> 1;                       // iterations

    bf16x8 afA[2][2], afB[2][2], bk[4][2];

    // ---- prologue: A(0),B(0) staged+retired; afA = A(0)q0; B(1) left in flight (4) --
    STG(0, 0, 0, 0); STG(0, 0, 1, 0);             // A(0)
    STG(0, 1, 0, 0); STG(0, 1, 1, 0);             // B(0)
    VMW(0);
    GBAR();
    LDAQ(afA, 0, 0);                              // A(0) q0 (completes before ph1 MFMA)
    STG(1, 1, 0, 64); STG(1, 1, 1, 64);           // B(1): 4 loads outstanding

    for (int j = 0; j < J - 1; ++j) {
        const int ka  = (j << 7);           // tile a = 2j     (buf0)
        const int kb1 = ka + 64;            // tile a+1        (buf1)
        const int ka2 = ka + 128;           // tile a+2
        const int ka3 = ka + 192;           // tile a+3
        // ---- ph1: MFMA a-q0 (afA); read a-q1 -> afB; B(a) frags ----
        LDBQ(0); LDAQ(afB, 0, 1); STG(1, 0, 0, kb1);
        GBAR(); P1(); MF16(0, afA); P0(); GBAR();
        // ---- ph2: MFMA a-q1 (afB); read a-q2 -> afA ----
        LDAQ(afA, 0, 2); STG(1, 0, 1, kb1);
        GBAR(); P1(); MF16(1, afB); P0(); GBAR();
        // ---- ph3: MFMA a-q2 (afA); read a-q3 -> afB ----
        LDAQ(afB, 0, 3); STG(0, 1, 0, ka2);
        GBAR(); P1(); MF16(2, afA); P0(); GBAR();
        // ---- ph4: retire {B(a+1),A(a+1)}; read (a+1)-q0 -> afA; MFMA a-q3 (afB) ----
        VMW(2); LDAQ(afA, 1, 0); STG(0, 1, 1, ka2);
        GBAR(); P1(); MF16(3, afB); P0(); GBAR();
        // ---- ph5: MFMA (a+1)-q0 (afA); B(a+1) frags; read q1 -> afB ----
        LDBQ(1); LDAQ(afB, 1, 1); STG(0, 0, 0, ka2);
        GBAR(); P1(); MF16(0, afA); P0(); GBAR();
        // ---- ph6 ----
        LDAQ(afA, 1, 2); STG(0, 0, 1, ka2);
        GBAR(); P1(); MF16(1, afB); P0(); GBAR();
        // ---- ph7 ----
        LDAQ(afB, 1, 3); STG(1, 1, 0, ka3);
        GBAR(); P1(); MF16(2, afA); P0(); GBAR();
        // ---- ph8: retire {B(a+2)stage, A(a+2)}; read (a+2)-q0 -> afA; MFMA (a+1)-q3 --
        VMW(2); LDAQ(afA, 0, 0); STG(1, 1, 1, ka3);
        GBAR(); P1(); MF16(3, afB); P0(); GBAR();
    }

    // ---- peeled final iteration (tiles NT-2, NT-1): stage only A(NT-1) ----
    {
        const int kb1 = ((NT - 1) << 6);
        LDBQ(0); LDAQ(afB, 0, 1); STG(1, 0, 0, kb1);
        GBAR(); P1(); MF16(0, afA); P0(); GBAR();
        LDAQ(afA, 0, 2); STG(1, 0, 1, kb1);
        GBAR(); P1(); MF16(1, afB); P0(); GBAR();
        LDAQ(afB, 0, 3);
        GBAR(); P1(); MF16(2, afA); P0(); GBAR();
        VMW(0); LDAQ(afA, 1, 0);
        GBAR(); P1(); MF16(3, afB); P0(); GBAR();
        LDBQ(1); LDAQ(afB, 1, 1);
        GBAR(); P1(); MF16(0, afA); P0(); GBAR();
        LDAQ(afA, 1, 2);
        GBAR(); P1(); MF16(1, afB); P0(); GBAR();
        LDAQ(afB, 1, 3);
        GBAR(); P1(); MF16(2, afA); P0(); GBAR();
        GBAR(); P1(); MF16(3, afB); P0();
    }

    // ---- epilogue ----
#pragma unroll
    for (int mi = 0; mi < 8; ++mi)
#pragma unroll
        for (int ni = 0; ni < 4; ++ni) {
            const int col = n0 + (wc << 6) + ni * 16 + (lane & 15);
#pragma unroll
            for (int r = 0; r < 4; ++r) {
                const int row = m0 + (wr << 7) + mi * 16 + ((lane >> 4) << 2) + r;
                const size_t idx = (size_t)row * N + col;
                if (MODE == 2) {
                    ((float*)C)[idx] = acc[mi][ni][r];
                } else if (MODE == 0) {
                    ((unsigned short*)C)[idx] = f2bf(acc[mi][ni][r]);
                } else {
                    float g = bf2f(((unsigned short*)C)[idx]);
                    float u = acc[mi][ni][r];
                    float h = (g / (1.0f + __expf(-g))) * u;
                    ((unsigned short*)C)[idx] = f2bf(h);
                }
            }
        }
}

// ================== FALLBACK (round-1 verified): in-loop dequant GEMMs ==============
__global__ __launch_bounds__(256, 2)
void gemm_gateup_fb(const unsigned short* __restrict__ Xr,
                    const int* __restrict__ Wg, const float* __restrict__ Sg,
                    const int* __restrict__ Wu, const float* __restrict__ Su,
                    unsigned short* __restrict__ H)
{
    __shared__ __align__(16) unsigned short lA [128 * 64];
    __shared__ __align__(16) unsigned short lBg[128 * 64];
    __shared__ __align__(16) unsigned short lBu[128 * 64];
    const int MT = T_DIM / 128;
    const int bid = blockIdx.x;
    const int m0 = (bid % MT) * 128;
    const int n0 = (bid / MT) * 128;
    const int tid  = threadIdx.x;
    const int lane = tid & 63;
    const int wid  = tid >> 6;
    const int wr = wid >> 1, wc = wid & 1;
    f32x4 accG[4][4], accU[4][4];
#pragma unroll
    for (int i = 0; i < 4; ++i)
#pragma unroll
        for (int j = 0; j < 4; ++j) { accG[i][j] = (f32x4)0.0f; accU[i][j] = (f32x4)0.0f; }
    const int arow = lane >> 3;
    const int acol = (lane & 7) * 8;
    const int SStride = D_DIM / GRP;
    for (int k0 = 0; k0 < D_DIM; k0 += 64) {
        __syncthreads();
#pragma unroll
        for (int it = 0; it < 4; ++it) {
            int chunk = wid * 4 + it;
            const unsigned short* gp = Xr + (size_t)(m0 + chunk * 8 + arow) * D_DIM + k0 + acol;
            __builtin_amdgcn_global_load_lds((gmem_void*)gp, (lds_void*)(lA + chunk * 512), 16, 0, 0);
        }
        const int g = k0 >> 7;
#pragma unroll
        for (int i = 0; i < 8; ++i) {
            int linear = i * 1024 + tid * 4;
            int r = linear >> 6;
            int c = linear & 63;
            const int32x4 wg = *reinterpret_cast<const int32x4*>(Wg + (size_t)(n0 + r) * D_DIM + k0 + c);
            const int32x4 wu = *reinterpret_cast<const int32x4*>(Wu + (size_t)(n0 + r) * D_DIM + k0 + c);
            float scg = Sg[(size_t)(n0 + r) * SStride + g];
            float scu = Su[(size_t)(n0 + r) * SStride + g];
            unsigned int g01 = (unsigned int)f2bf((float)(wg.x - 8) * scg) | ((unsigned int)f2bf((float)(wg.y - 8) * scg) << 16);
            unsigned int g23 = (unsigned int)f2bf((float)(wg.z - 8) * scg) | ((unsigned int)f2bf((float)(wg.w - 8) * scg) << 16);
            unsigned int u01 = (unsigned int)f2bf((float)(wu.x - 8) * scu) | ((unsigned int)f2bf((float)(wu.y - 8) * scu) << 16);
            unsigned int u23 = (unsigned int)f2bf((float)(wu.z - 8) * scu) | ((unsigned int)f2bf((float)(wu.w - 8) * scu) << 16);
            *reinterpret_cast<uint2*>(lBg + r * 64 + c) = make_uint2(g01, g23);
            *reinterpret_cast<uint2*>(lBu + r * 64 + c) = make_uint2(u01, u23);
        }
        __syncthreads();
#pragma unroll
        for (int ks = 0; ks < 2; ++ks) {
            const int koff = ks * 32 + (lane >> 4) * 8;
            bf16x8 af[4], bg[4], bu[4];
#pragma unroll
            for (int mi = 0; mi < 4; ++mi)
                af[mi] = *reinterpret_cast<const bf16x8*>(lA + (wr * 64 + mi * 16 + (lane & 15)) * 64 + koff);
#pragma unroll
            for (int ni = 0; ni < 4; ++ni) {
                bg[ni] = *reinterpret_cast<const bf16x8*>(lBg + (wc * 64 + ni * 16 + (lane & 15)) * 64 + koff);
                bu[ni] = *reinterpret_cast<const bf16x8*>(lBu + (wc * 64 + ni * 16 + (lane & 15)) * 64 + koff);
            }
#pragma unroll
            for (int mi = 0; mi < 4; ++mi)
#pragma unroll
                for (int ni = 0; ni < 4; ++ni) {
                    accG[mi][ni] = __builtin_amdgcn_mfma_f32_16x16x32_bf16(af[mi], bg[ni], accG[mi][ni], 0, 0, 0);
                    accU[mi][ni] = __builtin_amdgcn_mfma_f32_16x16x32_bf16(af[mi], bu[ni], accU[mi][ni], 0, 0, 0);
                }
        }
    }
#pragma unroll
    for (int mi = 0; mi < 4; ++mi)
#pragma unroll
        for (int ni = 0; ni < 4; ++ni) {
            const int col = n0 + wc * 64 + ni * 16 + (lane & 15);
#pragma unroll
            for (int r = 0; r < 4; ++r) {
                const int row = m0 + wr * 64 + mi * 16 + (lane >> 4) * 4 + r;
                float gv = accG[mi][ni][r];
                float uv = accU[mi][ni][r];
                float hv = (gv / (1.0f + __expf(-gv))) * uv;
                H[(size_t)row * I_DIM + col] = f2bf(hv);
            }
        }
}

__global__ __launch_bounds__(256, 2)
void gemm_down_fb(const unsigned short* __restrict__ Hr,
                  const int* __restrict__ Wd, const float* __restrict__ Sd,
                  float* __restrict__ Out)
{
    __shared__ __align__(16) unsigned short lA[128 * 64];
    __shared__ __align__(16) unsigned short lB[128 * 64];
    const int MT = T_DIM / 128;
    const int bid = blockIdx.x;
    const int m0 = (bid % MT) * 128;
    const int n0 = (bid / MT) * 128;
    const int tid  = threadIdx.x;
    const int lane = tid & 63;
    const int wid  = tid >> 6;
    const int wr = wid >> 1, wc = wid & 1;
    f32x4 acc[4][4];
#pragma unroll
    for (int i = 0; i < 4; ++i)
#pragma unroll
        for (int j = 0; j < 4; ++j) acc[i][j] = (f32x4)0.0f;
    const int arow = lane >> 3;
    const int acol = (lane & 7) * 8;
    const int SStride = I_DIM / GRP;
    for (int k0 = 0; k0 < I_DIM; k0 += 64) {
        __syncthreads();
#pragma unroll
        for (int it = 0; it < 4; ++it) {
            int chunk = wid * 4 + it;
            const unsigned short* gp = Hr + (size_t)(m0 + chunk * 8 + arow) * I_DIM + k0 + acol;
            __builtin_amdgcn_global_load_lds((gmem_void*)gp, (lds_void*)(lA + chunk * 512), 16, 0, 0);
        }
        const int g = k0 >> 7;
#pragma unroll
        for (int i = 0; i < 8; ++i) {
            int linear = i * 1024 + tid * 4;
            int r = linear >> 6;
            int c = linear & 63;
            const int32x4 wd = *reinterpret_cast<const int32x4*>(Wd + (size_t)(n0 + r) * I_DIM + k0 + c);
            float sc = Sd[(size_t)(n0 + r) * SStride + g];
            unsigned int d01 = (unsigned int)f2bf((float)(wd.x - 8) * sc) | ((unsigned int)f2bf((float)(wd.y - 8) * sc) << 16);
            unsigned int d23 = (unsigned int)f2bf((float)(wd.z - 8) * sc) | ((unsigned int)f2bf((float)(wd.w - 8) * sc) << 16);
            *reinterpret_cast<uint2*>(lB + r * 64 + c) = make_uint2(d01, d23);
        }
        __syncthreads();
#pragma unroll
        for (int ks = 0; ks < 2; ++ks) {
            const int koff = ks * 32 + (lane >> 4) * 8;
            bf16x8 af[4], bfr[4];
#pragma unroll
            for (int mi = 0; mi < 4; ++mi)
                af[mi] = *reinterpret_cast<const bf16x8*>(lA + (wr * 64 + mi * 16 + (lane & 15)) * 64 + koff);
#pragma unroll
            for (int ni = 0; ni < 4; ++ni)
                bfr[ni] = *reinterpret_cast<const bf16x8*>(lB + (wc * 64 + ni * 16 + (lane & 15)) * 64 + koff);
#pragma unroll
            for (int mi = 0; mi < 4; ++mi)
#pragma unroll
                for (int ni = 0; ni < 4; ++ni)
                    acc[mi][ni] = __builtin_amdgcn_mfma_f32_16x16x32_bf16(af[mi], bfr[ni], acc[mi][ni], 0, 0, 0);
        }
    }
#pragma unroll
    for (int mi = 0; mi < 4; ++mi)
#pragma unroll
        for (int ni = 0; ni < 4; ++ni) {
            const int col = n0 + wc * 64 + ni * 16 + (lane & 15);
#pragma unroll
            for (int r = 0; r < 4; ++r) {
                const int row = m0 + wr * 64 + mi * 16 + (lane >> 4) * 4 + r;
                Out[(size_t)row * D_DIM + col] = acc[mi][ni][r];
            }
        }
}

extern "C" void kernel_launch(void* const* d_in, const int* in_sizes, int n_in,
                              void* d_out, int out_size, void* d_ws, size_t ws_size,
                              hipStream_t stream) {
    const float* x       = (const float*)d_in[0];
    const int*   wq_gate = (const int*)d_in[1];
    const float* s_gate  = (const float*)d_in[2];
    const int*   wq_up   = (const int*)d_in[3];
    const float* s_up    = (const float*)d_in[4];
    const int*   wq_down = (const int*)d_in[5];
    const float* s_down  = (const float*)d_in[6];
    float* out = (float*)d_out;

    const size_t XR_E = (size_t)T_DIM * D_DIM;      // 16.8M
    const size_t H_E  = (size_t)T_DIM * I_DIM;      // 50.3M
    const size_t W_E  = (size_t)I_DIM * D_DIM;      // 50.3M
    const size_t need = (XR_E + H_E + 2 * W_E) * sizeof(unsigned short);  // 335.5 MB

    unsigned short* xr = (unsigned short*)d_ws;
    unsigned short* h  = xr + XR_E;

    // 1) xr = hadamard(x) -> bf16
    {
        int ngroups = (int)(XR_E / 128);
        had_f32_to_bf16<<<dim3(ngroups / 4), dim3(256), 0, stream>>>(x, xr, ngroups);
    }

    if (ws_size >= need) {
        unsigned short* wgbf = h + H_E;
        unsigned short* wubf = wgbf + W_E;
        int total8 = (int)(W_E / 8);
        // 2) pre-dequant gate & up weights -> bf16
        dequant_w<<<dim3((total8 + 255) / 256), dim3(256), 0, stream>>>(wq_gate, s_gate, wgbf, D_DIM, total8);
        dequant_w<<<dim3((total8 + 255) / 256), dim3(256), 0, stream>>>(wq_up,   s_up,   wubf, D_DIM, total8);
        // 3) gate = xr @ Wg^T  (bf16, into h)
        gemm256<0><<<dim3((T_DIM / 256) * (I_DIM / 256)), dim3(512), 0, stream>>>(
            xr, wgbf, (void*)h, T_DIM, I_DIM, D_DIM);
        // 4) h = silu(gate) * (xr @ Wu^T)   (fused epilogue, in place over h)
        gemm256<1><<<dim3((T_DIM / 256) * (I_DIM / 256)), dim3(512), 0, stream>>>(
            xr, wubf, (void*)h, T_DIM, I_DIM, D_DIM);
        // 5) h = hadamard(h) in place
        {
            int ngroups = (int)(H_E / 128);
            had_bf16_inplace<<<dim3(ngroups / 4), dim3(256), 0, stream>>>(h, ngroups);
        }
        // 6) dequant down weights (reuse gate buffer)
        dequant_w<<<dim3((total8 + 255) / 256), dim3(256), 0, stream>>>(wq_down, s_down, wgbf, I_DIM, total8);
        // 7) out = h @ Wd^T  (f32)
        gemm256<2><<<dim3((T_DIM / 256) * (D_DIM / 256)), dim3(512), 0, stream>>>(
            h, wgbf, (void*)out, T_DIM, D_DIM, I_DIM);
    } else {
        // fallback: round-1 verified path (in-loop dequant)
        gemm_gateup_fb<<<dim3((T_DIM / 128) * (I_DIM / 128)), dim3(256), 0, stream>>>(
            xr, wq_gate, s_gate, wq_up, s_up, h);
        {
            int ngroups = (int)(H_E / 128);
            had_bf16_inplace<<<dim3(ngroups / 4), dim3(256), 0, stream>>>(h, ngroups);
        }
        gemm_down_fb<<<dim3((T_DIM / 128) * (D_DIM / 128)), dim3(256), 0, stream>>>(
            h, wq_down, s_down, out);
    }
}